// Round 8
// baseline (826.967 us; speedup 1.0000x reference)
//
#include <hip/hip_runtime.h>
#include <hip/hip_bf16.h>

// Problem: N=4,C=64,F=100,T=200,H=16 ; B=N*F=400, BT=80000
// Pipeline per b-chunk (NB rows): ln1 (fp32->bf16 x) -> xg GEMM (MFMA bf16,
//   bf16 out, gate-permuted, coalesced ushort4 stores) -> LSTM recurrence
//   (4 chains/wave, asm-pinned register weights, batched 16-shfl h-broadcast,
//   depth-4 xg prefetch) -> attention (multiplicative causal mask BEFORE
//   softmax, suffix-V trick) -> combine+LN2+complex linear+LN3+PReLU+residual.
// ws: header 204800 B (bihh fp32 @0, Wih-bf16 @8192), then per chunk:
//   xr bf16 [NB][200][64], xi same, xg bf16 [24][200][NB][16][4],
//   h f32 [24][NB][200][16], att f32 [8][NB][200][16].
// Total = 204800 + NB*1,075,200  (NB=400 -> 430.3 MB, tried first).

typedef __attribute__((ext_vector_type(8))) short bf16x8;
typedef __attribute__((ext_vector_type(4))) float f32x4;

static __device__ __forceinline__ float bf2f(unsigned short u) {
  return __uint_as_float(((unsigned)u) << 16);
}
static __device__ __forceinline__ unsigned short f2bfu(float x) {
  __hip_bfloat16 h = __float2bfloat16(x);
  return *(unsigned short*)&h;
}
static __device__ __forceinline__ float sigf(float x) {
  return __fdividef(1.f, 1.f + __expf(-x));
}
static __device__ __forceinline__ float tanh_(float x) {
  return 1.f - __fdividef(2.f, __expf(2.f * x) + 1.f);  // safe at +-inf
}

// ---------------- kernel A: LN1 over C -> xr/xi bf16 [bl][t][c]
__global__ __launch_bounds__(256) void k_ln1(const float* __restrict__ in,
    const float* __restrict__ w, const float* __restrict__ bsh,
    unsigned short* __restrict__ xr, unsigned short* __restrict__ xi, int b0) {
  __shared__ float is[64][101];   // [c][(tloc,ri)]
  __shared__ float os[100][65];   // [(tloc,ri)][c]
  int bid = blockIdx.x;
  int nfl = bid >> 2, tile = bid & 3;         // NB nf-local x 4 tiles of 50 t
  int nf = b0 + nfl;
  int t0 = tile * 50;
  int n = nf / 100, f = nf - n * 100;
  int tid = threadIdx.x;
  for (int i = 0; i < 7; ++i) {               // 64 rows x 25 float4
    int idx = tid + i * 256;
    if (idx < 1600) {
      int c = idx / 25, q = idx - c * 25;
      float4 v = *(const float4*)(in + (size_t)((n * 64 + c) * 100 + f) * 400
                                  + t0 * 2 + q * 4);
      is[c][q*4+0] = v.x; is[c][q*4+1] = v.y; is[c][q*4+2] = v.z; is[c][q*4+3] = v.w;
    }
  }
  __syncthreads();
  if (tid < 100) {
    float s = 0.f, ss = 0.f;
    #pragma unroll
    for (int c = 0; c < 64; ++c) { float v = is[c][tid]; s += v; ss += v * v; }
    float mean = s * 0.015625f;
    float var  = ss * 0.015625f - mean * mean;
    float rstd = rsqrtf(var + 1e-5f);
    #pragma unroll
    for (int c = 0; c < 64; ++c)
      os[tid][c] = (is[c][tid] - mean) * rstd * w[c] + bsh[c];
  }
  __syncthreads();
  for (int ri = 0; ri < 2; ++ri) {
    unsigned short* dst = ri ? xi : xr;
    for (int i = 0; i < 4; ++i) {             // 50 rows x 16 ushort4 per ri
      int idx = tid + i * 256;
      if (idx < 800) {
        int t = idx >> 4, q = idx & 15;
        ushort4 v;
        v.x = f2bfu(os[t*2+ri][q*4+0]); v.y = f2bfu(os[t*2+ri][q*4+1]);
        v.z = f2bfu(os[t*2+ri][q*4+2]); v.w = f2bfu(os[t*2+ri][q*4+3]);
        *(ushort4*)(dst + ((size_t)nfl * 200 + t0 + t) * 64 + q * 4) = v;
      }
    }
  }
}

// ---------------- prep: bihh = bih + bhh ; wbf = bf16(Wih)
__global__ void k_prep(const float* __restrict__ bih, const float* __restrict__ bhh,
                       const float* __restrict__ Wih, float* __restrict__ bihh,
                       unsigned short* __restrict__ wbf) {
  int i = blockIdx.x * 256 + threadIdx.x;
  if (i < 1536) bihh[i] = bih[i] + bhh[i];
  if (i < 98304) wbf[i] = f2bfu(Wih[i]);
}

// ---------------- kernel B: xg = x_sel @ Wih[l]^T + bihh[l] via MFMA bf16.
__global__ __launch_bounds__(256) void k_xg(const unsigned short* __restrict__ xr,
    const unsigned short* __restrict__ xi, const unsigned short* __restrict__ wbf,
    const float* __restrict__ bihh, unsigned short* __restrict__ xg,
    int M, int NB, int nsb) {
  int tid = threadIdx.x;
  int wave = tid >> 6, lane = tid & 63;
  int bid = blockIdx.x;
  int l = bid / nsb, sb = bid - l * nsb;
  int sub = sb * 4 + wave;
  int m0 = sub * 16;
  if (m0 >= M) return;
  int sel = (0xE54770 >> l) & 1;                 // per-lstm real/imag selection
  const unsigned short* xs = sel ? xi : xr;
  int n = lane & 15, q = lane >> 4;
  int mr = m0 + n; if (mr >= M) mr = M - 1;      // clamp A rows (stores guarded)
  const unsigned short* xrow = xs + (size_t)mr * 64;
  bf16x8 a0 = *(const bf16x8*)(xrow + q * 8);        // c = q*8+e
  bf16x8 a1 = *(const bf16x8*)(xrow + 32 + q * 8);   // c = 32+q*8+e
  int mq = m0 + q * 4;
  int bl = mq / 200, tt = mq - bl * 200;
  size_t ob[4]; bool okm[4];
  #pragma unroll
  for (int r = 0; r < 4; ++r) {
    okm[r] = (mq + r) < M;
    ob[r] = ((size_t)(l * 200 + tt) * NB + bl) * 64;
    ++tt; if (tt == 200) { tt = 0; ++bl; }
  }
  const unsigned short* wbase = wbf + l * 4096;
  f32x4 acc[4];
  float bi[4];
  #pragma unroll
  for (int jt = 0; jt < 4; ++jt) {               // j = jt*16 + n ; k=n, g=jt
    const unsigned short* wrow = wbase + (jt * 16 + n) * 64;
    bf16x8 b0 = *(const bf16x8*)(wrow + q * 8);
    bf16x8 b1 = *(const bf16x8*)(wrow + 32 + q * 8);
    f32x4 a = {0.f, 0.f, 0.f, 0.f};
    a = __builtin_amdgcn_mfma_f32_16x16x32_bf16(a0, b0, a, 0, 0, 0);
    acc[jt] = __builtin_amdgcn_mfma_f32_16x16x32_bf16(a1, b1, a, 0, 0, 0);
    bi[jt] = bihh[l * 64 + jt * 16 + n];
  }
  #pragma unroll
  for (int r = 0; r < 4; ++r) {
    if (!okm[r]) continue;
    ushort4 o;
    o.x = f2bfu(acc[0][r] + bi[0]);
    o.y = f2bfu(acc[1][r] + bi[1]);
    o.z = f2bfu(acc[2][r] + bi[2]);
    o.w = f2bfu(acc[3][r] + bi[3]);
    *(ushort4*)(xg + ob[r] + n * 4) = o;         // coalesced 8B store
  }
}

// ---------------- kernel R: LSTM recurrence. 1 wave per block = 4 chains.
// lane=(bl=lane>>4 chain, k=lane&15). 64 weights in NAMED scalar VGPRs,
// asm-pinned so the compiler CANNOT sink the loads into the loop (r7's
// VGPR=56 proved demotion). 16 shfls issued as one batch -> single DS
// round-trip per step. Depth-4 xg prefetch.
__global__ __launch_bounds__(64, 2) void k_lstm(const unsigned short* __restrict__ xg,
    const float* __restrict__ Whh, float* __restrict__ hbuf, int NB) {
  int lane = threadIdx.x;
  int bl = lane >> 4, k = lane & 15;
  int chain = blockIdx.x * 4 + bl;        // 24*NB chains, 6*NB blocks
  int l = chain / NB, b = chain - l * NB;
  int grp = lane & 48;
  const float* W = Whh + (size_t)l * 1024;
  const float* wip = W + k * 16;          // gate i row
  const float* wfp = W + (16 + k) * 16;   // gate f row
  const float* wgp = W + (32 + k) * 16;   // gate g row
  const float* wop = W + (48 + k) * 16;   // gate o row
  float wi0=wip[0],wi1=wip[1],wi2=wip[2],wi3=wip[3],wi4=wip[4],wi5=wip[5],
        wi6=wip[6],wi7=wip[7],wi8=wip[8],wi9=wip[9],wi10=wip[10],wi11=wip[11],
        wi12=wip[12],wi13=wip[13],wi14=wip[14],wi15=wip[15];
  float wf0=wfp[0],wf1=wfp[1],wf2=wfp[2],wf3=wfp[3],wf4=wfp[4],wf5=wfp[5],
        wf6=wfp[6],wf7=wfp[7],wf8=wfp[8],wf9=wfp[9],wf10=wfp[10],wf11=wfp[11],
        wf12=wfp[12],wf13=wfp[13],wf14=wfp[14],wf15=wfp[15];
  float wg0=wgp[0],wg1=wgp[1],wg2=wgp[2],wg3=wgp[3],wg4=wgp[4],wg5=wgp[5],
        wg6=wgp[6],wg7=wgp[7],wg8=wgp[8],wg9=wgp[9],wg10=wgp[10],wg11=wgp[11],
        wg12=wgp[12],wg13=wgp[13],wg14=wgp[14],wg15=wgp[15];
  float wo0=wop[0],wo1=wop[1],wo2=wop[2],wo3=wop[3],wo4=wop[4],wo5=wop[5],
        wo6=wop[6],wo7=wop[7],wo8=wop[8],wo9=wop[9],wo10=wop[10],wo11=wop[11],
        wo12=wop[12],wo13=wop[13],wo14=wop[14],wo15=wop[15];
  // pin: compiler must keep these VGPR-resident (no remat / sinking)
  asm volatile("" : "+v"(wi0),"+v"(wi1),"+v"(wi2),"+v"(wi3),"+v"(wi4),
    "+v"(wi5),"+v"(wi6),"+v"(wi7),"+v"(wi8),"+v"(wi9),"+v"(wi10),"+v"(wi11),
    "+v"(wi12),"+v"(wi13),"+v"(wi14),"+v"(wi15));
  asm volatile("" : "+v"(wf0),"+v"(wf1),"+v"(wf2),"+v"(wf3),"+v"(wf4),
    "+v"(wf5),"+v"(wf6),"+v"(wf7),"+v"(wf8),"+v"(wf9),"+v"(wf10),"+v"(wf11),
    "+v"(wf12),"+v"(wf13),"+v"(wf14),"+v"(wf15));
  asm volatile("" : "+v"(wg0),"+v"(wg1),"+v"(wg2),"+v"(wg3),"+v"(wg4),
    "+v"(wg5),"+v"(wg6),"+v"(wg7),"+v"(wg8),"+v"(wg9),"+v"(wg10),"+v"(wg11),
    "+v"(wg12),"+v"(wg13),"+v"(wg14),"+v"(wg15));
  asm volatile("" : "+v"(wo0),"+v"(wo1),"+v"(wo2),"+v"(wo3),"+v"(wo4),
    "+v"(wo5),"+v"(wo6),"+v"(wo7),"+v"(wo8),"+v"(wo9),"+v"(wo10),"+v"(wo11),
    "+v"(wo12),"+v"(wo13),"+v"(wo14),"+v"(wo15));
  const unsigned short* xgp = xg + ((size_t)l * 200 * NB + b) * 64 + k * 4;
  size_t tstride = (size_t)NB * 64;       // ushorts per t step
  float* hp = hbuf + ((size_t)l * NB + b) * 3200 + k;
  float h = 0.f, c = 0.f;
  ushort4 u0 = *(const ushort4*)(xgp);
  ushort4 u1 = *(const ushort4*)(xgp + tstride);
  ushort4 u2 = *(const ushort4*)(xgp + 2 * tstride);
  ushort4 u3 = *(const ushort4*)(xgp + 3 * tstride);
  int tcur = 0;
#define LSTEP(BUF, TN) { \
  float hv0=__shfl(h,grp+0,64),  hv1=__shfl(h,grp+1,64); \
  float hv2=__shfl(h,grp+2,64),  hv3=__shfl(h,grp+3,64); \
  float hv4=__shfl(h,grp+4,64),  hv5=__shfl(h,grp+5,64); \
  float hv6=__shfl(h,grp+6,64),  hv7=__shfl(h,grp+7,64); \
  float hv8=__shfl(h,grp+8,64),  hv9=__shfl(h,grp+9,64); \
  float hv10=__shfl(h,grp+10,64),hv11=__shfl(h,grp+11,64); \
  float hv12=__shfl(h,grp+12,64),hv13=__shfl(h,grp+13,64); \
  float hv14=__shfl(h,grp+14,64),hv15=__shfl(h,grp+15,64); \
  float p0 = bf2f(BUF.x), p1 = bf2f(BUF.y); \
  float p2 = bf2f(BUF.z), p3 = bf2f(BUF.w); \
  p0+=wi0*hv0;   p1+=wf0*hv0;   p2+=wg0*hv0;   p3+=wo0*hv0; \
  p0+=wi1*hv1;   p1+=wf1*hv1;   p2+=wg1*hv1;   p3+=wo1*hv1; \
  p0+=wi2*hv2;   p1+=wf2*hv2;   p2+=wg2*hv2;   p3+=wo2*hv2; \
  p0+=wi3*hv3;   p1+=wf3*hv3;   p2+=wg3*hv3;   p3+=wo3*hv3; \
  p0+=wi4*hv4;   p1+=wf4*hv4;   p2+=wg4*hv4;   p3+=wo4*hv4; \
  p0+=wi5*hv5;   p1+=wf5*hv5;   p2+=wg5*hv5;   p3+=wo5*hv5; \
  p0+=wi6*hv6;   p1+=wf6*hv6;   p2+=wg6*hv6;   p3+=wo6*hv6; \
  p0+=wi7*hv7;   p1+=wf7*hv7;   p2+=wg7*hv7;   p3+=wo7*hv7; \
  p0+=wi8*hv8;   p1+=wf8*hv8;   p2+=wg8*hv8;   p3+=wo8*hv8; \
  p0+=wi9*hv9;   p1+=wf9*hv9;   p2+=wg9*hv9;   p3+=wo9*hv9; \
  p0+=wi10*hv10; p1+=wf10*hv10; p2+=wg10*hv10; p3+=wo10*hv10; \
  p0+=wi11*hv11; p1+=wf11*hv11; p2+=wg11*hv11; p3+=wo11*hv11; \
  p0+=wi12*hv12; p1+=wf12*hv12; p2+=wg12*hv12; p3+=wo12*hv12; \
  p0+=wi13*hv13; p1+=wf13*hv13; p2+=wg13*hv13; p3+=wo13*hv13; \
  p0+=wi14*hv14; p1+=wf14*hv14; p2+=wg14*hv14; p3+=wo14*hv14; \
  p0+=wi15*hv15; p1+=wf15*hv15; p2+=wg15*hv15; p3+=wo15*hv15; \
  float ig_ = sigf(p0), fg_ = sigf(p1); \
  float gg_ = tanh_(p2), og_ = sigf(p3); \
  c = fg_ * c + ig_ * gg_; \
  h = og_ * tanh_(c); \
  hp[tcur * 16] = h; ++tcur; \
  BUF = *(const ushort4*)(xgp + (size_t)(TN) * tstride); }
  for (int it = 0; it < 50; ++it) {
    int t4 = it * 4;
    int n0 = t4 + 4; if (n0 > 199) n0 = 199;
    int n1 = t4 + 5; if (n1 > 199) n1 = 199;
    int n2 = t4 + 6; if (n2 > 199) n2 = 199;
    int n3 = t4 + 7; if (n3 > 199) n3 = 199;
    LSTEP(u0, n0)
    LSTEP(u1, n1)
    LSTEP(u2, n2)
    LSTEP(u3, n3)
  }
#undef LSTEP
}

// ---------------- kernel C: attention per (branch, bl). Multiplicative causal
// mask before softmax: masked s get weight exp(0); handled via suffix-V init.
__global__ __launch_bounds__(256) void k_attn(const float* __restrict__ hbuf,
                                              float* __restrict__ att, int NB) {
  __shared__ float Q[200][17];
  __shared__ float K[200][16];
  __shared__ float V[200][16];
  __shared__ float Vs[200][17];
  int bid = blockIdx.x;                 // 8 br x NB
  int br = bid / NB, b = bid - br * NB;
  int tid = threadIdx.x;
  const float* qg = hbuf + ((size_t)(br * 3 + 0) * NB + b) * 3200;
  const float* kg = hbuf + ((size_t)(br * 3 + 1) * NB + b) * 3200;
  const float* vg = hbuf + ((size_t)(br * 3 + 2) * NB + b) * 3200;
  for (int i = 0; i < 4; ++i) {         // 200 rows x 4 f4 each of Q,K,V
    int idx = tid + i * 256;
    if (idx < 800) {
      int t = idx >> 2, q = idx & 3;
      float4 a = *(const float4*)(qg + t * 16 + q * 4);
      Q[t][q*4+0] = a.x; Q[t][q*4+1] = a.y; Q[t][q*4+2] = a.z; Q[t][q*4+3] = a.w;
      *(float4*)&K[t][q * 4] = *(const float4*)(kg + t * 16 + q * 4);
      *(float4*)&V[t][q * 4] = *(const float4*)(vg + t * 16 + q * 4);
    }
  }
  __syncthreads();
  if (tid < 16) {                       // suffix sums of V
    float acc = 0.f;
    Vs[199][tid] = 0.f;
    for (int t = 198; t >= 0; --t) { acc += V[t + 1][tid]; Vs[t][tid] = acc; }
  }
  __syncthreads();
  if (tid < 200) {
    int t = tid;
    float q0[16], va[16];
    #pragma unroll
    for (int k = 0; k < 16; ++k) q0[k] = Q[t][k] * 0.25f;   // fold /sqrt(16)
    #pragma unroll
    for (int k = 0; k < 16; ++k) va[k] = Vs[t][k];          // masked: weight exp(0)=1
    float S = (float)(199 - t);
    for (int s = 0; s <= t; ++s) {
      float e = 0.f;
      #pragma unroll
      for (int k = 0; k < 16; ++k) e += q0[k] * K[s][k];
      float wgt = __expf(e);
      S += wgt;
      #pragma unroll
      for (int k = 0; k < 16; ++k) va[k] += wgt * V[s][k];
    }
    float inv = __fdividef(1.f, S);
    float* dst = att + (((size_t)br * NB + b) * 200 + t) * 16;
    #pragma unroll
    for (int q = 0; q < 4; ++q) {
      float4 v; v.x = va[q*4+0]*inv; v.y = va[q*4+1]*inv;
      v.z = va[q*4+2]*inv; v.w = va[q*4+3]*inv;
      *(float4*)(dst + q * 4) = v;
    }
  }
}

// ---------------- kernel D: combine branches + LN2 + complex linear + LN3 +
// PReLU + residual, with LDS transpose for coalesced [N,C,F,T,2] IO.
__global__ __launch_bounds__(256) void k_out(const float* __restrict__ att,
    const float* __restrict__ in,
    const float* __restrict__ ln2w, const float* __restrict__ ln2b,
    const float* __restrict__ lrw, const float* __restrict__ lrb,
    const float* __restrict__ liw, const float* __restrict__ lib,
    const float* __restrict__ ln3w, const float* __restrict__ ln3b,
    const float* __restrict__ pa, float* __restrict__ out, int b0, int NB) {
  __shared__ float as_[8][40][17];
  __shared__ float ys[40][2][17];
  __shared__ float zs[64][81];
  int bid = blockIdx.x;                 // NB nf-local x 5 tiles of 40 t
  int nfl = bid / 5, tile = bid - nfl * 5;
  int nf = b0 + nfl;
  int t0 = tile * 40;
  int n = nf / 100, f = nf - n * 100;
  int tid = threadIdx.x;
  for (int i = 0; i < 5; ++i) {         // att: 8 br x 40 t x 4 f4
    int idx = tid + i * 256;
    int br = idx / 160, r = idx - br * 160;
    int t = r >> 2, q = r & 3;
    float4 v = *(const float4*)(att + (((size_t)br * NB + nfl) * 200 + t0 + t) * 16 + q * 4);
    as_[br][t][q*4+0] = v.x; as_[br][t][q*4+1] = v.y;
    as_[br][t][q*4+2] = v.z; as_[br][t][q*4+3] = v.w;
  }
  __syncthreads();
  if (tid < 80) {                       // combine + LN2 per (t,ri)
    int t = tid >> 1, ri = tid & 1;
    float vv[16]; float s = 0.f, ss = 0.f;
    #pragma unroll
    for (int k = 0; k < 16; ++k) {
      float v;
      if (ri == 0) v = as_[0][t][k] - as_[1][t][k] - as_[2][t][k] - as_[3][t][k];
      else         v = as_[4][t][k] + as_[5][t][k] + as_[6][t][k] - as_[7][t][k];
      vv[k] = v; s += v; ss += v * v;
    }
    float mean = s * 0.0625f;
    float var  = ss * 0.0625f - mean * mean;
    float rstd = rsqrtf(var + 1e-5f);
    #pragma unroll
    for (int k = 0; k < 16; ++k)
      ys[t][ri][k] = (vv[k] - mean) * rstd * ln2w[k] + ln2b[k];
  }
  __syncthreads();
  // complex linear 16->64 + LN3 over c (wave = 64 lanes = c) + PReLU
  int wv = tid >> 6, cc = tid & 63;
  float lr[16], li[16];
  #pragma unroll
  for (int q = 0; q < 4; ++q) {
    float4 v = *(const float4*)(lrw + cc * 16 + q * 4);
    lr[q*4+0] = v.x; lr[q*4+1] = v.y; lr[q*4+2] = v.z; lr[q*4+3] = v.w;
    float4 u = *(const float4*)(liw + cc * 16 + q * 4);
    li[q*4+0] = u.x; li[q*4+1] = u.y; li[q*4+2] = u.z; li[q*4+3] = u.w;
  }
  float brc = lrb[cc], bic = lib[cc];
  float w3 = ln3w[cc], b3 = ln3b[cc];
  float aP = pa[0];
  for (int tt = wv; tt < 40; tt += 4) {
    float zr = brc - bic, zi = brc + bic;
    #pragma unroll
    for (int k = 0; k < 16; ++k) {
      float yr = ys[tt][0][k], yi = ys[tt][1][k];
      zr += yr * lr[k] - yi * li[k];
      zi += yi * lr[k] + yr * li[k];
    }
    float s1 = zr, s2 = zr * zr, s3 = zi, s4 = zi * zi;
    #pragma unroll
    for (int m = 1; m < 64; m <<= 1) {
      s1 += __shfl_xor(s1, m, 64);
      s2 += __shfl_xor(s2, m, 64);
      s3 += __shfl_xor(s3, m, 64);
      s4 += __shfl_xor(s4, m, 64);
    }
    float mr = s1 * 0.015625f, vr = s2 * 0.015625f - mr * mr;
    float mi = s3 * 0.015625f, vi = s4 * 0.015625f - mi * mi;
    float r1 = (zr - mr) * rsqrtf(vr + 1e-5f) * w3 + b3;
    float r2 = (zi - mi) * rsqrtf(vi + 1e-5f) * w3 + b3;
    r1 = r1 >= 0.f ? r1 : aP * r1;
    r2 = r2 >= 0.f ? r2 : aP * r2;
    zs[cc][tt * 2 + 0] = r1;
    zs[cc][tt * 2 + 1] = r2;
  }
  __syncthreads();
  for (int i = 0; i < 5; ++i) {         // residual + coalesced write
    int idx = tid + i * 256;            // 64 c x 20 f4
    int c = idx / 20, q = idx - c * 20;
    size_t gaddr = (size_t)((n * 64 + c) * 100 + f) * 400 + t0 * 2 + q * 4;
    float4 v = *(const float4*)(in + gaddr);
    float4 z;
    z.x = zs[c][q*4+0] + v.x; z.y = zs[c][q*4+1] + v.y;
    z.z = zs[c][q*4+2] + v.z; z.w = zs[c][q*4+3] + v.w;
    *(float4*)(out + gaddr) = z;
  }
}

extern "C" void kernel_launch(void* const* d_in, const int* in_sizes, int n_in,
                              void* d_out, int out_size, void* d_ws, size_t ws_size,
                              hipStream_t stream) {
  (void)in_sizes; (void)n_in; (void)out_size;
  const float* inputs = (const float*)d_in[0];
  const float* Wih  = (const float*)d_in[1];
  const float* Whh  = (const float*)d_in[2];
  const float* bih  = (const float*)d_in[3];
  const float* bhh  = (const float*)d_in[4];
  const float* ln1w = (const float*)d_in[5];
  const float* ln1b = (const float*)d_in[6];
  const float* ln2w = (const float*)d_in[7];
  const float* ln2b = (const float*)d_in[8];
  const float* lrw  = (const float*)d_in[9];
  const float* lrb  = (const float*)d_in[10];
  const float* liw  = (const float*)d_in[11];
  const float* lib  = (const float*)d_in[12];
  const float* ln3w = (const float*)d_in[13];
  const float* ln3b = (const float*)d_in[14];
  const float* pa   = (const float*)d_in[15];
  float* out = (float*)d_out;
  char* ws = (char*)d_ws;

  // pick largest chunk NB (400,200,100,50,25) whose buffers fit ws_size
  int NB = 400;
  while (NB > 25 && 204800ull + (size_t)NB * 1075200ull > ws_size) NB /= 2;
  int nch = 400 / NB;

  float* bihh = (float*)(ws + 0);                        // 6 KB
  unsigned short* wbf = (unsigned short*)(ws + 8192);    // 192 KB bf16 Wih
  size_t o_xr = 204800;
  size_t o_xi = o_xr + (size_t)NB * 25600;
  size_t o_xg = o_xi + (size_t)NB * 25600;
  size_t o_h  = o_xg + (size_t)NB * 614400;
  size_t o_at = o_h  + (size_t)NB * 307200;
  unsigned short* xr = (unsigned short*)(ws + o_xr);
  unsigned short* xi = (unsigned short*)(ws + o_xi);
  unsigned short* xg = (unsigned short*)(ws + o_xg);
  float* hbuf = (float*)(ws + o_h);
  float* att  = (float*)(ws + o_at);

  k_prep<<<384, 256, 0, stream>>>(bih, bhh, Wih, bihh, wbf);
  int M = NB * 200;
  int nsb = (M + 63) >> 6;              // 64 m-rows per block (4 waves x 16)
  for (int ch = 0; ch < nch; ++ch) {
    int b0 = ch * NB;
    k_ln1 <<<NB * 4,   256, 0, stream>>>(inputs, ln1w, ln1b, xr, xi, b0);
    k_xg  <<<24 * nsb, 256, 0, stream>>>(xr, xi, wbf, bihh, xg, M, NB, nsb);
    k_lstm<<<NB * 6,    64, 0, stream>>>(xg, Whh, hbuf, NB);   // 1 wave = 4 chains
    k_attn<<<8 * NB,   256, 0, stream>>>(hbuf, att, NB);
    k_out <<<NB * 5,   256, 0, stream>>>(att, inputs, ln2w, ln2b, lrw, lrb,
                                         liw, lib, ln3w, ln3b, pa, out, b0, NB);
  }
}